// Round 16
// baseline (168.504 us; speedup 1.0000x reference)
//
#include <hip/hip_runtime.h>

// Capsule dynamic routing via MFMA, fused, u_hat never materialized.
//   x: [B=64, In=2048, K=16] fp32;  W: [N=32, In=2048, D=32, K=16] fp32
//   out v: [B=64, N=32, D=32] fp32
// Identities: b_t = u_hat . Vsum (logits linear in agreements); c_1 = 1/32.
// Per (n,i): u[d,b] = W[n,i] (32x16) @ x^T (16x64) via 2 b-tiles of
// mfma_f32_32x32x16_bf16.
// Structure (round-15 best = 162.9 us):
//   kT   : x -> xh/xl bf16 [In][B][K]
//   kS1c : iter-1 s (uniform c=1/32) + W->Wb convert (rounded-Wb accum)
//   kA   : logits (single MFMA, Wb*xh), chunk=8
//   kSM  : softmax over n (in-place, bf16 ct)
//   kS   : weighted sum (Wb, x hi+lo — output path keeps full x accuracy)
//   kR1h/kR2 : wide reduction + squash; 4-wave block partial-reduce of spart
//   in kS1c/kS via padded LDS -> spart 32 chunks (4.2 MB).
// Round 16: unroll 2->4 on kS1c/kA ii-loops. r12 proved kS1c is
// dep-chain-bound (occupancy-null, all pipes <8%); 4 independent
// load->round8->MFMA chains per wave doubles outstanding W-loads.
// NOTE (round-3): tiny-grid / long-serial-chain reductions are latency traps.
// NOTE (rounds 5/8/9): cross-pass fusion lost 30-160 us every time.

#define INP 2048
#define BB 64
#define KK 16
#define NN 32
#define DD 32
#define ICH 16
#define NCHUNK (INP / ICH)  // 128 i-chunks
#define NGRP (NCHUNK / 4)   // 32 spart chunks (4-wave block reduce)
#define ACH 8
#define ANCH (INP / ACH)    // 256 (kA)

typedef __attribute__((ext_vector_type(8))) short short8;
typedef __attribute__((ext_vector_type(16))) float f32x16;

__device__ __forceinline__ short bf_trunc(float f) {
  return (short)(__builtin_bit_cast(unsigned, f) >> 16);
}
__device__ __forceinline__ unsigned short bf_round(float f) {
  unsigned u = __builtin_bit_cast(unsigned, f);
  return (unsigned short)((u + 0x8000u) >> 16);
}
__device__ __forceinline__ float bf2f(unsigned short u) {
  return __builtin_bit_cast(float, (unsigned)u << 16);
}

__device__ __forceinline__ void split8(float4 w0, float4 w1, short8& h, short8& l) {
  float f[8] = {w0.x, w0.y, w0.z, w0.w, w1.x, w1.y, w1.z, w1.w};
#pragma unroll
  for (int j = 0; j < 8; ++j) {
    unsigned u = __builtin_bit_cast(unsigned, f[j]);
    h[j] = (short)(u >> 16);
    float hf = __builtin_bit_cast(float, u & 0xFFFF0000u);
    l[j] = bf_trunc(f[j] - hf);
  }
}

// round-to-nearest bf16 of 8 fp32 (for the stored Wb)
__device__ __forceinline__ short8 round8(float4 w0, float4 w1) {
  float f[8] = {w0.x, w0.y, w0.z, w0.w, w1.x, w1.y, w1.z, w1.w};
  short8 r;
#pragma unroll
  for (int j = 0; j < 8; ++j) r[j] = (short)bf_round(f[j]);
  return r;
}

// ------------------------------------------------------------------ kT
// transpose x [B][In][K] fp32 -> xt_hi/xt_lo [In][B][K] bf16
__global__ __launch_bounds__(256) void kT(const float* __restrict__ x,
                                          short* __restrict__ xh,
                                          short* __restrict__ xl) {
  const int t = blockIdx.x * 256 + threadIdx.x; // In*B = 131072
  const int i = t >> 6, b = t & 63;
  const float4* xs = (const float4*)(x + ((size_t)b * INP + i) * KK);
  short8* dh = (short8*)(xh + ((size_t)i * BB + b) * KK);
  short8* dl = (short8*)(xl + ((size_t)i * BB + b) * KK);
#pragma unroll
  for (int h = 0; h < 2; ++h) {
    short8 hh, ll;
    split8(xs[h * 2], xs[h * 2 + 1], hh, ll);
    dh[h] = hh;
    dl[h] = ll;
  }
}

// cross-wave (4-wave) reduce of s0/s1 through padded LDS, then write spart.
// lds[4][64][33]: bank = (lane + r) & 31 -> conflict-free. Each wave writes
// 8 of the 32 (r) values of the block-sum.
__device__ __forceinline__ void block_reduce_store(
    float lds[4][64][33], const f32x16& s0, const f32x16& s1, int wv, int lane,
    int bl, int hi, unsigned short* __restrict__ spart, size_t off, float scale) {
#pragma unroll
  for (int r = 0; r < 16; ++r) {
    lds[wv][lane][r] = s0[r];
    lds[wv][lane][r + 16] = s1[r];
  }
  __syncthreads();
#pragma unroll
  for (int j = 0; j < 8; ++j) {
    const int rp = wv * 8 + j;
    const float sum = lds[0][lane][rp] + lds[1][lane][rp] +
                      lds[2][lane][rp] + lds[3][lane][rp];
    const int rr = rp & 15;
    const int d = (rr & 3) + 8 * (rr >> 2) + 4 * hi;
    const int b = bl + (rp >> 4) * 32;
    spart[off + d * BB + b] = bf_round(scale * sum);
  }
}

// ------------------------------------------------------------------ kS1c
// iteration 1 (c uniform = 1/32) + W->bf16 conversion. Block = (n, 4 adjacent
// i-chunks of 16); accumulates from ROUNDED Wb (single MFMA per b-tile);
// 4-wave block reduce -> spart[32 grp]. unroll 4: 4 load->round->MFMA chains.
__global__ __launch_bounds__(256) void kS1c(const float* __restrict__ W,
                                            const short* __restrict__ xh,
                                            short* __restrict__ Wb,
                                            unsigned short* __restrict__ spart) {
  __shared__ float lds[4][64][33];
  const int wv = threadIdx.x >> 6;
  const int lane = threadIdx.x & 63;
  const int bl = lane & 31;
  const int hi = lane >> 5;
  const int n = blockIdx.x >> 5;       // 32 n
  const int chg = blockIdx.x & 31;     // 32 chunk-groups
  const int ch = chg * 4 + wv;         // this wave's i-chunk

  f32x16 s0 = {};
  f32x16 s1 = {};

  const size_t fragoff = (((size_t)n * INP + (size_t)ch * ICH) * DD + bl) * KK + hi * 8;
  const float* Wp = W + fragoff;
  short* Wbp = Wb + fragoff;
  const short* xhp = xh + (size_t)ch * ICH * BB * KK + hi * 8;

#pragma unroll 4
  for (int ii = 0; ii < ICH; ++ii) {
    float4 w0 = *(const float4*)(Wp + (size_t)ii * (DD * KK));
    float4 w1 = *(const float4*)(Wp + (size_t)ii * (DD * KK) + 4);
    const short8 wb = round8(w0, w1);
    *(short8*)(Wbp + (size_t)ii * (DD * KK)) = wb; // store Wb
    const short8 x0h = *(const short8*)(xhp + ii * (BB * KK) + bl * KK);
    const short8 x1h = *(const short8*)(xhp + ii * (BB * KK) + (bl + 32) * KK);
    s0 = __builtin_amdgcn_mfma_f32_32x32x16_bf16(wb, x0h, s0, 0, 0, 0);
    s1 = __builtin_amdgcn_mfma_f32_32x32x16_bf16(wb, x1h, s1, 0, 0, 0);
  }

  const size_t off = ((size_t)chg * NN + n) * (DD * BB);
  block_reduce_store(lds, s0, s1, wv, lane, bl, hi, spart, off, 0.03125f);
}

// ------------------------------------------------------------------ kA
// wave = (n, i-chunk of 8). a[b,n,i] = sum_d u[d,b]*vsum[b,n,d] -> ct bf16.
// single-MFMA u (x hi only): logit error is softmax-damped + i-averaged.
// unroll 4 for deeper load pipelining.
__global__ __launch_bounds__(256) void kA(const short* __restrict__ Wb,
                                          const short* __restrict__ xh,
                                          const float* __restrict__ vsum,
                                          unsigned short* __restrict__ ct) {
  const int wv = threadIdx.x >> 6;
  const int lane = threadIdx.x & 63;
  const int bl = lane & 31;
  const int hi = lane >> 5;
  const int w = blockIdx.x * 4 + wv;
  const int n = w >> 8;           // / ANCH
  const int ch = w & (ANCH - 1);

  float vr0[16], vr1[16];
#pragma unroll
  for (int r = 0; r < 16; ++r) {
    const int d = (r & 3) + 8 * (r >> 2) + 4 * hi;
    vr0[r] = vsum[((size_t)n * DD + d) * BB + bl];
    vr1[r] = vsum[((size_t)n * DD + d) * BB + bl + 32];
  }

  const short* Wp = Wb + (((size_t)n * INP + (size_t)ch * ACH) * DD + bl) * KK + hi * 8;
  const short* xhp = xh + (size_t)ch * ACH * BB * KK + hi * 8;

#pragma unroll 4
  for (int ii = 0; ii < ACH; ++ii) {
    const short8 whi = *(const short8*)(Wp + (size_t)ii * (DD * KK));
    const short8 x0h = *(const short8*)(xhp + ii * (BB * KK) + bl * KK);
    const short8 x1h = *(const short8*)(xhp + ii * (BB * KK) + (bl + 32) * KK);

    f32x16 u0 = {};
    u0 = __builtin_amdgcn_mfma_f32_32x32x16_bf16(whi, x0h, u0, 0, 0, 0);
    f32x16 u1 = {};
    u1 = __builtin_amdgcn_mfma_f32_32x32x16_bf16(whi, x1h, u1, 0, 0, 0);

    float p0 = 0.f, p1 = 0.f;
#pragma unroll
    for (int r = 0; r < 16; ++r) {
      p0 += u0[r] * vr0[r];
      p1 += u1[r] * vr1[r];
    }
    p0 += __shfl_xor(p0, 32, 64);
    p1 += __shfl_xor(p1, 32, 64);
    const int i = ch * ACH + ii;
    ct[((size_t)i * NN + n) * BB + lane] = bf_round((lane < 32) ? p0 : p1);
  }
}

// ------------------------------------------------------------------ kSM
// in-place softmax over n for each (i, b); wave per i, lane = b. bf16 ct.
__global__ __launch_bounds__(256) void kSM(unsigned short* __restrict__ ct) {
  const int wv = threadIdx.x >> 6;
  const int lane = threadIdx.x & 63;
  const int i = blockIdx.x * 4 + wv;
  unsigned short* p = ct + (size_t)i * NN * BB + lane;
  float a[NN];
  float m = -1e30f;
#pragma unroll
  for (int n = 0; n < NN; ++n) {
    a[n] = bf2f(p[n * BB]);
    m = fmaxf(m, a[n]);
  }
  float s = 0.f;
#pragma unroll
  for (int n = 0; n < NN; ++n) {
    a[n] = __expf(a[n] - m);
    s += a[n];
  }
  const float inv = 1.f / s;
#pragma unroll
  for (int n = 0; n < NN; ++n) p[n * BB] = bf_round(a[n] * inv);
}

// ------------------------------------------------------------------ kS
// iterations 2-3: block = (n, 4 adjacent i-chunks of 16). s_acc += c * u;
// 4-wave block reduce -> spart[32 grp]. Output path keeps x hi+lo.
__global__ __launch_bounds__(256) void kS(const short* __restrict__ Wb,
                                          const short* __restrict__ xh,
                                          const short* __restrict__ xl,
                                          const unsigned short* __restrict__ ct,
                                          unsigned short* __restrict__ spart) {
  __shared__ float lds[4][64][33];
  const int wv = threadIdx.x >> 6;
  const int lane = threadIdx.x & 63;
  const int bl = lane & 31;
  const int hi = lane >> 5;
  const int n = blockIdx.x >> 5;
  const int chg = blockIdx.x & 31;
  const int ch = chg * 4 + wv;

  f32x16 s0 = {};
  f32x16 s1 = {};

  const short* Wp = Wb + (((size_t)n * INP + (size_t)ch * ICH) * DD + bl) * KK + hi * 8;
  const short* xhp = xh + (size_t)ch * ICH * BB * KK + hi * 8;
  const short* xlp = xl + (size_t)ch * ICH * BB * KK + hi * 8;

#pragma unroll 2
  for (int ii = 0; ii < ICH; ++ii) {
    const short8 whi = *(const short8*)(Wp + (size_t)ii * (DD * KK));
    const short8 x0h = *(const short8*)(xhp + ii * (BB * KK) + bl * KK);
    const short8 x0l = *(const short8*)(xlp + ii * (BB * KK) + bl * KK);
    const short8 x1h = *(const short8*)(xhp + ii * (BB * KK) + (bl + 32) * KK);
    const short8 x1l = *(const short8*)(xlp + ii * (BB * KK) + (bl + 32) * KK);

    f32x16 u0 = {};
    u0 = __builtin_amdgcn_mfma_f32_32x32x16_bf16(whi, x0h, u0, 0, 0, 0);
    u0 = __builtin_amdgcn_mfma_f32_32x32x16_bf16(whi, x0l, u0, 0, 0, 0);
    f32x16 u1 = {};
    u1 = __builtin_amdgcn_mfma_f32_32x32x16_bf16(whi, x1h, u1, 0, 0, 0);
    u1 = __builtin_amdgcn_mfma_f32_32x32x16_bf16(whi, x1l, u1, 0, 0, 0);

    const int i = ch * ICH + ii;
    const float c0 = bf2f(ct[((size_t)i * NN + n) * BB + bl]);
    const float c1 = bf2f(ct[((size_t)i * NN + n) * BB + bl + 32]);
#pragma unroll
    for (int r = 0; r < 16; ++r) {
      s0[r] += c0 * u0[r];
      s1[r] += c1 * u1[r];
    }
  }

  const size_t off = ((size_t)chg * NN + n) * (DD * BB);
  block_reduce_store(lds, s0, s1, wv, lane, bl, hi, spart, off, 1.0f);
}

// ------------------------------------------------------------------ kR1h
// bf16 spart [32][N][D][B] -> st fp32; uint loads (2 elems/thread).
__global__ void kR1h(const unsigned* __restrict__ spart, float2* __restrict__ st) {
  const int t = blockIdx.x * 128 + threadIdx.x; // 32768 uint cells
  float s0 = 0.f, s1 = 0.f;
  for (int g = 0; g < NGRP; ++g) {
    const unsigned u = spart[(size_t)g * (NN * DD * BB / 2) + t];
    s0 += bf2f((unsigned short)(u & 0xFFFFu));
    s1 += bf2f((unsigned short)(u >> 16));
  }
  st[t] = make_float2(s0, s1);
}

// ------------------------------------------------------------------ kR2
// squash per (b,n); vsum = (first ? v : vsum + v); write out on last.
__global__ void kR2(const float* __restrict__ st, float* __restrict__ vsum,
                    float* __restrict__ out, int first, int last) {
  const int t = blockIdx.x * 64 + threadIdx.x; // B*N = 2048
  const int b = t & 63;
  const int n = t >> 6;
  float sd[DD];
  float s2 = 0.f;
#pragma unroll
  for (int d = 0; d < DD; ++d) {
    sd[d] = st[(n * DD + d) * BB + b];
    s2 += sd[d] * sd[d];
  }
  const float scale = s2 / (1.f + s2) / sqrtf(s2 + 1e-7f);
#pragma unroll
  for (int d = 0; d < DD; ++d) {
    const float v = scale * sd[d];
    const size_t idx = (size_t)(n * DD + d) * BB + b;
    vsum[idx] = first ? v : (vsum[idx] + v);
    if (last) out[((size_t)b * NN + n) * DD + d] = v;
  }
}

extern "C" void kernel_launch(void* const* d_in, const int* in_sizes, int n_in,
                              void* d_out, int out_size, void* d_ws,
                              size_t ws_size, hipStream_t stream) {
  const float* x = (const float*)d_in[0]; // [64,2048,16]
  const float* W = (const float*)d_in[1]; // [32,2048,32,16]
  float* out = (float*)d_out;             // [64,32,32]

  short* xh = (short*)d_ws;                            // [In][B][K] bf16 4.2 MB
  short* xl = xh + (size_t)INP * BB * KK;              // 4.2 MB
  short* Wbuf = xl + (size_t)INP * BB * KK;            // [N][In][D][K] bf16 67 MB
  unsigned short* ct = (unsigned short*)(Wbuf + (size_t)NN * INP * DD * KK); // 8.4 MB
  unsigned short* sparth = ct + (size_t)INP * NN * BB; // [32][N][D][B] bf16 4.2 MB
  float* st = (float*)(sparth + (size_t)NGRP * NN * DD * BB); // 256 KB
  float* vsum = st + (size_t)NN * DD * BB;                     // 256 KB

  const int gW = NN * NGRP;                  // 1024 blocks (n x chunk-group)
  const int gA = (NN * ANCH) / 4;            // 2048 blocks
  const int gT = (INP * BB) / 256;           // 512
  const int gSM = INP / 4;                   // 512
  const int gR1h = (NN * DD * BB / 2) / 128; // 256
  const int gR2 = (BB * NN) / 64;            // 32

  kT<<<gT, 256, 0, stream>>>(x, xh, xl);

  // iteration 1: c uniform; also converts W -> Wb; vsum = v (first)
  kS1c<<<gW, 256, 0, stream>>>(W, xh, Wbuf, sparth);
  kR1h<<<gR1h, 128, 0, stream>>>((const unsigned*)sparth, (float2*)st);
  kR2<<<gR2, 64, 0, stream>>>(st, vsum, out, 1, 0);
  // iterations 2..3 on bf16 W
  for (int it = 1; it < 3; ++it) {
    kA<<<gA, 256, 0, stream>>>(Wbuf, xh, vsum, ct);
    kSM<<<gSM, 256, 0, stream>>>(ct);
    kS<<<gW, 256, 0, stream>>>(Wbuf, xh, xl, ct, sparth);
    kR1h<<<gR1h, 128, 0, stream>>>((const unsigned*)sparth, (float2*)st);
    kR2<<<gR2, 64, 0, stream>>>(st, vsum, out, 0, it == 2);
  }
}